// Round 6
// baseline (239.679 us; speedup 1.0000x reference)
//
#include <hip/hip_runtime.h>

#define R   256
#define S   128
#define CM  256
#define CH  32
#define CZ  128

typedef __attribute__((ext_vector_type(8))) short short8;
typedef __attribute__((ext_vector_type(4))) float f32x4;
typedef unsigned short ushort_t;

__device__ inline ushort_t f2bf(float f) {
    union { float f; unsigned u; } v; v.f = f;
    unsigned u = v.u;
    unsigned r = u + 0x7FFF + ((u >> 16) & 1);
    return (ushort_t)(r >> 16);
}

// ---------------------------------------------------------------------------
// K0 (merged prep):
//   blocks [0,256):   scale[i*R+j] = 1/(1e-3 + sum_s mask[s,i]*mask[s,j])
//   blocks [256,384): WTp[z][e*32+c] = bf16(w_out[c*32+e][z])
//   blocks [384,448): WcatT[ch][k]   = bf16(ch<32 ? w1[k][ch] : w2[k][ch-32])
// ---------------------------------------------------------------------------
__global__ __launch_bounds__(256) void k_prep(
    const float* __restrict__ mask, const float* __restrict__ w_out,
    const float* __restrict__ w1, const float* __restrict__ w2,
    float* __restrict__ scale, ushort_t* __restrict__ WTp,
    ushort_t* __restrict__ WcatT) {
    int b = blockIdx.x, t = threadIdx.x;
    if (b < 256) {
        int i = b, j = t;
        float acc = 0.f;
        for (int s = 0; s < S; ++s) acc += mask[s * R + i] * mask[s * R + j];
        scale[i * R + j] = 1.0f / (1e-3f + acc);
    } else if (b < 384) {
        int z = b - 256;
        #pragma unroll
        for (int q = 0; q < 4; ++q) {
            int k2 = q * 256 + t;
            int e = k2 >> 5, c = k2 & 31;
            WTp[(size_t)z * 1024 + k2] = f2bf(w_out[(size_t)(c * 32 + e) * CZ + z]);
        }
    } else {
        int ch = b - 384, k = t;
        const float* w = (ch < CH) ? w1 : w2;
        WcatT[(size_t)ch * CM + k] = f2bf(w[(size_t)k * CH + (ch & 31)]);
    }
}

// ---------------------------------------------------------------------------
// K1: LN + both projections via MFMA (unchanged).
// Writes Abig[(r*32+c)][s], BbigT[(r*32+e)][s] (bf16), mask pre-applied.
// ---------------------------------------------------------------------------
__global__ __launch_bounds__(256) void k_lnproj(
    const float* __restrict__ m, const float* __restrict__ mask,
    const float* __restrict__ g, const float* __restrict__ beta,
    const float* __restrict__ b1, const float* __restrict__ b2,
    const ushort_t* __restrict__ WcatT,
    ushort_t* __restrict__ Abig, ushort_t* __restrict__ BbigT) {
    __shared__ ushort_t mnL[64 * CM];
    __shared__ ushort_t wL[64 * CM];
    int t = threadIdx.x;
    int sg = blockIdx.x & 7, rg = blockIdx.x >> 3;
    int s0 = sg * 16, r0 = rg * 4;

    int ml = t >> 2, part = t & 3;
    int r_l = ml >> 4, s_l = ml & 15;
    size_t p = (size_t)(s0 + s_l) * R + (r0 + r_l);
    const float4* row = (const float4*)(m + p * CM + part * 64);
    float4 x[16];
    float sum = 0.f, sq = 0.f;
    #pragma unroll
    for (int i = 0; i < 16; ++i) {
        x[i] = row[i];
        sum += x[i].x + x[i].y + x[i].z + x[i].w;
        sq  += x[i].x * x[i].x + x[i].y * x[i].y
             + x[i].z * x[i].z + x[i].w * x[i].w;
    }
    sum += __shfl_xor(sum, 1); sum += __shfl_xor(sum, 2);
    sq  += __shfl_xor(sq, 1);  sq  += __shfl_xor(sq, 2);
    float mean = sum * (1.0f / CM);
    float var  = sq * (1.0f / CM) - mean * mean;
    float inv  = rsqrtf(var + 1e-5f);
    const float4* g4 = (const float4*)(g + part * 64);
    const float4* be4 = (const float4*)(beta + part * 64);
    #pragma unroll
    for (int c8 = 0; c8 < 8; ++c8) {
        float4 a = x[2 * c8], b = x[2 * c8 + 1];
        float4 ga = g4[2 * c8], gb = g4[2 * c8 + 1];
        float4 ba = be4[2 * c8], bb = be4[2 * c8 + 1];
        union { ushort_t u[8]; uint4 v; } pk;
        pk.u[0] = f2bf((a.x - mean) * inv * ga.x + ba.x);
        pk.u[1] = f2bf((a.y - mean) * inv * ga.y + ba.y);
        pk.u[2] = f2bf((a.z - mean) * inv * ga.z + ba.z);
        pk.u[3] = f2bf((a.w - mean) * inv * ga.w + ba.w);
        pk.u[4] = f2bf((b.x - mean) * inv * gb.x + bb.x);
        pk.u[5] = f2bf((b.y - mean) * inv * gb.y + bb.y);
        pk.u[6] = f2bf((b.z - mean) * inv * gb.z + bb.z);
        pk.u[7] = f2bf((b.w - mean) * inv * gb.w + bb.w);
        int ck = part * 8 + c8;
        int phys = ck ^ (ml & 15);
        *(uint4*)&mnL[ml * CM + phys * 8] = pk.v;
    }
    #pragma unroll
    for (int it = 0; it < 8; ++it) {
        int v = t + it * 256;
        int ch = v >> 5, ck = v & 31;
        int phys = ck ^ (ch & 15);
        *(uint4*)&wL[ch * CM + phys * 8] =
            *(const uint4*)&WcatT[(size_t)ch * CM + ck * 8];
    }
    __syncthreads();

    int w = t >> 6, lane = t & 63, quad = lane >> 4, l15 = lane & 15;
    int ch = w * 16 + l15;
    f32x4 acc[4];
    #pragma unroll
    for (int a = 0; a < 4; a++) acc[a] = (f32x4)(0.f);
    #pragma unroll
    for (int ks = 0; ks < 8; ++ks) {
        int cb = ks * 4 + quad;
        short8 bfr = *(const short8*)&wL[ch * CM + ((cb ^ l15) << 3)];
        #pragma unroll
        for (int mt = 0; mt < 4; ++mt) {
            int mm = mt * 16 + l15;
            short8 afr = *(const short8*)&mnL[mm * CM + ((cb ^ l15) << 3)];
            acc[mt] = __builtin_amdgcn_mfma_f32_16x16x32_bf16(afr, bfr, acc[mt], 0, 0, 0);
        }
    }

    int c = ch & 31;
    float bias = (ch < CH) ? b1[c] : b2[c];
    ushort_t* dst = (ch < CH) ? Abig : BbigT;
    #pragma unroll
    for (int mt = 0; mt < 4; ++mt) {
        int r = r0 + mt;
        union { ushort_t u[4]; uint2 v; } pk;
        #pragma unroll
        for (int reg = 0; reg < 4; ++reg) {
            int s = s0 + quad * 4 + reg;
            float mv = mask[(size_t)s * R + r];
            pk.u[reg] = f2bf((acc[mt][reg] + bias) * mv);
        }
        *(uint2*)&dst[((size_t)r * CH + c) * S + s0 + quad * 4] = pk.v;
    }
}

// ---------------------------------------------------------------------------
// K2: bf16 MFMA GEMM  D[m][n] = sum_k Abig[m][k] * BbigT[n][k]
// OC layout: OC[(il*R + j)*1024 + e*32 + c]  (coalesced 8B lane stores).
// ---------------------------------------------------------------------------
__global__ __launch_bounds__(256) void k_outer(
    const ushort_t* __restrict__ Abig, const ushort_t* __restrict__ BbigT,
    ushort_t* __restrict__ OC, int ib) {
    __shared__ ushort_t shA[128 * 128];
    __shared__ ushort_t shB[128 * 128];
    int t = threadIdx.x;
    int mb = ib * CH + blockIdx.y * 128;
    int nb = blockIdx.x * 128;

    #pragma unroll
    for (int it = 0; it < 8; ++it) {
        int v = t + it * 256;
        int row = v >> 4, chk = v & 15;
        int sw = (chk ^ (row & 7)) << 3;
        *(float4*)&shA[row * 128 + sw] =
            *(const float4*)&Abig[(size_t)(mb + row) * S + (chk << 3)];
        *(float4*)&shB[row * 128 + sw] =
            *(const float4*)&BbigT[(size_t)(nb + row) * S + (chk << 3)];
    }
    __syncthreads();

    int w = t >> 6, lane = t & 63;
    int quad = lane >> 4, l15 = lane & 15;
    int wm = (w & 1) * 64, wn = (w >> 1) * 64;

    f32x4 acc[4][4];
    #pragma unroll
    for (int a = 0; a < 4; a++)
        #pragma unroll
        for (int b = 0; b < 4; b++) acc[a][b] = (f32x4)(0.f);

    #pragma unroll
    for (int ks = 0; ks < 4; ++ks) {
        int qk = ks * 4 + quad;
        short8 af[4], bfr[4];
        #pragma unroll
        for (int mt = 0; mt < 4; ++mt) {
            int mm = wm + mt * 16 + l15;
            af[mt] = *(const short8*)&shA[mm * 128 + ((qk ^ (mm & 7)) << 3)];
        }
        #pragma unroll
        for (int nt = 0; nt < 4; ++nt) {
            int nn = wn + nt * 16 + l15;
            bfr[nt] = *(const short8*)&shB[nn * 128 + ((qk ^ (nn & 7)) << 3)];
        }
        #pragma unroll
        for (int mt = 0; mt < 4; ++mt)
            #pragma unroll
            for (int nt = 0; nt < 4; ++nt)
                acc[mt][nt] = __builtin_amdgcn_mfma_f32_16x16x32_bf16(
                    af[mt], bfr[nt], acc[mt][nt], 0, 0, 0);
    }

    #pragma unroll
    for (int mt = 0; mt < 4; ++mt) {
        int lmb = blockIdx.y * 128 + wm + mt * 16;
        int il = lmb >> 5;
        int cb = (lmb & 31) + quad * 4;
        #pragma unroll
        for (int nt = 0; nt < 4; ++nt) {
            int gnb = nb + wn + nt * 16;
            int j = gnb >> 5;
            int e = (gnb & 31) + l15;
            union { ushort_t u[4]; uint2 v; } pk;
            #pragma unroll
            for (int reg = 0; reg < 4; ++reg)
                pk.u[reg] = f2bf(acc[mt][nt][reg]);
            *(uint2*)&OC[(((size_t)il * R + j) << 10) + e * 32 + cb] = pk.v;
        }
    }
}

// ---------------------------------------------------------------------------
// K3: out[p][z] = (sum_k2 OC[p][k2] * WTp[z][k2] + b_out[z]) * scale[p]
// 32 rows/block, 4 waves K-split (256 k2 each), grid CI*8 (4 blocks/CU).
// Explicit 2-deep software pipeline: slice kk+1 loads in flight during
// slice kk's MFMAs.  LDS K-reduction, 132-stride (conflict-free).
// ---------------------------------------------------------------------------
__global__ __launch_bounds__(256, 2) void k_proj(
    const ushort_t* __restrict__ OC, const ushort_t* __restrict__ WTp,
    const float* __restrict__ b_out, const float* __restrict__ scale,
    float* __restrict__ out, int ib) {
    __shared__ float red[32 * 132];      // 16.9 KB
    int t = threadIdx.x;
    int w = t >> 6, lane = t & 63;
    int quad = lane >> 4, l15 = lane & 15;
    int rb = blockIdx.x * 32;            // chunk-local pair row base

    const ushort_t* pA = OC + ((size_t)rb + l15) * 1024 + w * 256 + quad * 8;
    const ushort_t* pW = WTp + (size_t)l15 * 1024 + w * 256 + quad * 8;

    f32x4 acc[2][8];
    #pragma unroll
    for (int a = 0; a < 2; a++)
        #pragma unroll
        for (int b = 0; b < 8; b++) acc[a][b] = (f32x4)(0.f);

    short8 aX[2], wX[8], aY[2], wY[8];
    // preload slice 0
    #pragma unroll
    for (int mt = 0; mt < 2; ++mt) aX[mt] = *(const short8*)&pA[mt * 16 * 1024];
    #pragma unroll
    for (int nt = 0; nt < 8; ++nt) wX[nt] = *(const short8*)&pW[nt * 16 * 1024];

    #pragma unroll
    for (int kk = 0; kk < 8; kk += 2) {
        int o1 = (kk + 1) * 32;
        #pragma unroll
        for (int mt = 0; mt < 2; ++mt)
            aY[mt] = *(const short8*)&pA[o1 + mt * 16 * 1024];
        #pragma unroll
        for (int nt = 0; nt < 8; ++nt)
            wY[nt] = *(const short8*)&pW[o1 + nt * 16 * 1024];
        #pragma unroll
        for (int mt = 0; mt < 2; ++mt)
            #pragma unroll
            for (int nt = 0; nt < 8; ++nt)
                acc[mt][nt] = __builtin_amdgcn_mfma_f32_16x16x32_bf16(
                    aX[mt], wX[nt], acc[mt][nt], 0, 0, 0);
        int o2 = (kk + 2 < 8 ? kk + 2 : kk + 1) * 32;   // clamp: dummy reload
        #pragma unroll
        for (int mt = 0; mt < 2; ++mt)
            aX[mt] = *(const short8*)&pA[o2 + mt * 16 * 1024];
        #pragma unroll
        for (int nt = 0; nt < 8; ++nt)
            wX[nt] = *(const short8*)&pW[o2 + nt * 16 * 1024];
        #pragma unroll
        for (int mt = 0; mt < 2; ++mt)
            #pragma unroll
            for (int nt = 0; nt < 8; ++nt)
                acc[mt][nt] = __builtin_amdgcn_mfma_f32_16x16x32_bf16(
                    aY[mt], wY[nt], acc[mt][nt], 0, 0, 0);
    }

    // ---- cross-wave K-reduction through LDS ----
    if (w == 3) {
        #pragma unroll
        for (int mt = 0; mt < 2; ++mt)
            #pragma unroll
            for (int nt = 0; nt < 8; ++nt)
                #pragma unroll
                for (int reg = 0; reg < 4; ++reg)
                    red[(mt * 16 + quad * 4 + reg) * 132 + nt * 16 + l15] =
                        acc[mt][nt][reg];
    }
    __syncthreads();
    if (w == 2) {
        #pragma unroll
        for (int mt = 0; mt < 2; ++mt)
            #pragma unroll
            for (int nt = 0; nt < 8; ++nt)
                #pragma unroll
                for (int reg = 0; reg < 4; ++reg)
                    red[(mt * 16 + quad * 4 + reg) * 132 + nt * 16 + l15] +=
                        acc[mt][nt][reg];
    }
    __syncthreads();
    if (w == 1) {
        #pragma unroll
        for (int mt = 0; mt < 2; ++mt)
            #pragma unroll
            for (int nt = 0; nt < 8; ++nt)
                #pragma unroll
                for (int reg = 0; reg < 4; ++reg)
                    red[(mt * 16 + quad * 4 + reg) * 132 + nt * 16 + l15] +=
                        acc[mt][nt][reg];
    }
    __syncthreads();
    if (w == 0) {
        float bz[8];
        #pragma unroll
        for (int nt = 0; nt < 8; ++nt) bz[nt] = b_out[nt * 16 + l15];
        #pragma unroll
        for (int mt = 0; mt < 2; ++mt) {
            #pragma unroll
            for (int reg = 0; reg < 4; ++reg) {
                int p = rb + mt * 16 + quad * 4 + reg;
                int pg = ib * R + p;
                float sc = scale[pg];
                #pragma unroll
                for (int nt = 0; nt < 8; ++nt) {
                    float v = acc[mt][nt][reg] +
                        red[(mt * 16 + quad * 4 + reg) * 132 + nt * 16 + l15];
                    out[(size_t)pg * CZ + nt * 16 + l15] = (v + bz[nt]) * sc;
                }
            }
        }
    }
}

// ---------------------------------------------------------------------------
extern "C" void kernel_launch(void* const* d_in, const int* in_sizes, int n_in,
                              void* d_out, int out_size, void* d_ws, size_t ws_size,
                              hipStream_t stream) {
    const float* m    = (const float*)d_in[0];
    const float* mask = (const float*)d_in[1];
    const float* g    = (const float*)d_in[2];
    const float* be   = (const float*)d_in[3];
    const float* w1   = (const float*)d_in[4];
    const float* b1   = (const float*)d_in[5];
    const float* w2   = (const float*)d_in[6];
    const float* b2   = (const float*)d_in[7];
    const float* wo   = (const float*)d_in[8];
    const float* bo   = (const float*)d_in[9];
    float* out = (float*)d_out;

    char* ws = (char*)d_ws;
    ushort_t* Abig  = (ushort_t*)ws;                        // 2 MB
    ushort_t* BbigT = Abig + (size_t)R * CH * S;            // 2 MB
    ushort_t* WTp   = BbigT + (size_t)R * CH * S;           // 256 KB
    ushort_t* WcatT = WTp + (size_t)CZ * CH * CH;           // 32 KB
    float*    scale = (float*)(WcatT + (size_t)64 * CM);    // 256 KB
    ushort_t* OC    = (ushort_t*)(scale + (size_t)R * R);   // CI*512 KB

    size_t fixed = (size_t)R * CH * S * 2 * 2 + (size_t)CZ * CH * CH * 2
                 + (size_t)64 * CM * 2 + (size_t)R * R * 4;
    int CI = 128;    // chunk = 64 MB: L3-resident OC, reused across chunks
    while (CI > 4 && fixed + (size_t)CI * R * CH * CH * 2 > ws_size)
        CI >>= 1;

    k_prep<<<448, 256, 0, stream>>>(mask, wo, w1, w2, scale, WTp, WcatT);
    k_lnproj<<<512, 256, 0, stream>>>(m, mask, g, be, b1, b2, WcatT, Abig, BbigT);
    for (int ib = 0; ib < R; ib += CI) {
        dim3 go(64, CI / 4);
        k_outer<<<go, 256, 0, stream>>>(Abig, BbigT, OC, ib);
        k_proj<<<CI * 8, 256, 0, stream>>>(OC, WTp, bo, scale, out, ib);
    }
}

// Round 7
// 164.444 us; speedup vs baseline: 1.4575x; 1.4575x over previous
//
#include <hip/hip_runtime.h>

#define R   256
#define S   128
#define CM  256
#define CH  32
#define CZ  128

typedef __attribute__((ext_vector_type(8))) short short8;
typedef __attribute__((ext_vector_type(4))) float f32x4;
typedef unsigned short ushort_t;

__device__ inline ushort_t f2bf(float f) {
    union { float f; unsigned u; } v; v.f = f;
    unsigned u = v.u;
    unsigned r = u + 0x7FFF + ((u >> 16) & 1);
    return (ushort_t)(r >> 16);
}

// ---------------------------------------------------------------------------
// K0 (merged prep):
//   blocks [0,256):   scale[i*R+j] = 1/(1e-3 + sum_s mask[s,i]*mask[s,j])
//   blocks [256,384): WTp[z][e*32+c] = bf16(w_out[c*32+e][z])
//   blocks [384,448): WcatT[ch][k]   = bf16(ch<32 ? w1[k][ch] : w2[k][ch-32])
// ---------------------------------------------------------------------------
__global__ __launch_bounds__(256) void k_prep(
    const float* __restrict__ mask, const float* __restrict__ w_out,
    const float* __restrict__ w1, const float* __restrict__ w2,
    float* __restrict__ scale, ushort_t* __restrict__ WTp,
    ushort_t* __restrict__ WcatT) {
    int b = blockIdx.x, t = threadIdx.x;
    if (b < 256) {
        int i = b, j = t;
        float acc = 0.f;
        for (int s = 0; s < S; ++s) acc += mask[s * R + i] * mask[s * R + j];
        scale[i * R + j] = 1.0f / (1e-3f + acc);
    } else if (b < 384) {
        int z = b - 256;
        #pragma unroll
        for (int q = 0; q < 4; ++q) {
            int k2 = q * 256 + t;
            int e = k2 >> 5, c = k2 & 31;
            WTp[(size_t)z * 1024 + k2] = f2bf(w_out[(size_t)(c * 32 + e) * CZ + z]);
        }
    } else {
        int ch = b - 384, k = t;
        const float* w = (ch < CH) ? w1 : w2;
        WcatT[(size_t)ch * CM + k] = f2bf(w[(size_t)k * CH + (ch & 31)]);
    }
}

// ---------------------------------------------------------------------------
// K1: LN + both projections via MFMA (validated in R3-R6).
// Writes Abig[(r*32+c)][s], BbigT[(r*32+e)][s] (bf16), mask pre-applied.
// ---------------------------------------------------------------------------
__global__ __launch_bounds__(256) void k_lnproj(
    const float* __restrict__ m, const float* __restrict__ mask,
    const float* __restrict__ g, const float* __restrict__ beta,
    const float* __restrict__ b1, const float* __restrict__ b2,
    const ushort_t* __restrict__ WcatT,
    ushort_t* __restrict__ Abig, ushort_t* __restrict__ BbigT) {
    __shared__ ushort_t mnL[64 * CM];
    __shared__ ushort_t wL[64 * CM];
    int t = threadIdx.x;
    int sg = blockIdx.x & 7, rg = blockIdx.x >> 3;
    int s0 = sg * 16, r0 = rg * 4;

    int ml = t >> 2, part = t & 3;
    int r_l = ml >> 4, s_l = ml & 15;
    size_t p = (size_t)(s0 + s_l) * R + (r0 + r_l);
    const float4* row = (const float4*)(m + p * CM + part * 64);
    float4 x[16];
    float sum = 0.f, sq = 0.f;
    #pragma unroll
    for (int i = 0; i < 16; ++i) {
        x[i] = row[i];
        sum += x[i].x + x[i].y + x[i].z + x[i].w;
        sq  += x[i].x * x[i].x + x[i].y * x[i].y
             + x[i].z * x[i].z + x[i].w * x[i].w;
    }
    sum += __shfl_xor(sum, 1); sum += __shfl_xor(sum, 2);
    sq  += __shfl_xor(sq, 1);  sq  += __shfl_xor(sq, 2);
    float mean = sum * (1.0f / CM);
    float var  = sq * (1.0f / CM) - mean * mean;
    float inv  = rsqrtf(var + 1e-5f);
    const float4* g4 = (const float4*)(g + part * 64);
    const float4* be4 = (const float4*)(beta + part * 64);
    #pragma unroll
    for (int c8 = 0; c8 < 8; ++c8) {
        float4 a = x[2 * c8], b = x[2 * c8 + 1];
        float4 ga = g4[2 * c8], gb = g4[2 * c8 + 1];
        float4 ba = be4[2 * c8], bb = be4[2 * c8 + 1];
        union { ushort_t u[8]; uint4 v; } pk;
        pk.u[0] = f2bf((a.x - mean) * inv * ga.x + ba.x);
        pk.u[1] = f2bf((a.y - mean) * inv * ga.y + ba.y);
        pk.u[2] = f2bf((a.z - mean) * inv * ga.z + ba.z);
        pk.u[3] = f2bf((a.w - mean) * inv * ga.w + ba.w);
        pk.u[4] = f2bf((b.x - mean) * inv * gb.x + bb.x);
        pk.u[5] = f2bf((b.y - mean) * inv * gb.y + bb.y);
        pk.u[6] = f2bf((b.z - mean) * inv * gb.z + bb.z);
        pk.u[7] = f2bf((b.w - mean) * inv * gb.w + bb.w);
        int ck = part * 8 + c8;
        int phys = ck ^ (ml & 15);
        *(uint4*)&mnL[ml * CM + phys * 8] = pk.v;
    }
    #pragma unroll
    for (int it = 0; it < 8; ++it) {
        int v = t + it * 256;
        int ch = v >> 5, ck = v & 31;
        int phys = ck ^ (ch & 15);
        *(uint4*)&wL[ch * CM + phys * 8] =
            *(const uint4*)&WcatT[(size_t)ch * CM + ck * 8];
    }
    __syncthreads();

    int w = t >> 6, lane = t & 63, quad = lane >> 4, l15 = lane & 15;
    int ch = w * 16 + l15;
    f32x4 acc[4];
    #pragma unroll
    for (int a = 0; a < 4; a++) acc[a] = (f32x4)(0.f);
    #pragma unroll
    for (int ks = 0; ks < 8; ++ks) {
        int cb = ks * 4 + quad;
        short8 bfr = *(const short8*)&wL[ch * CM + ((cb ^ l15) << 3)];
        #pragma unroll
        for (int mt = 0; mt < 4; ++mt) {
            int mm = mt * 16 + l15;
            short8 afr = *(const short8*)&mnL[mm * CM + ((cb ^ l15) << 3)];
            acc[mt] = __builtin_amdgcn_mfma_f32_16x16x32_bf16(afr, bfr, acc[mt], 0, 0, 0);
        }
    }

    int c = ch & 31;
    float bias = (ch < CH) ? b1[c] : b2[c];
    ushort_t* dst = (ch < CH) ? Abig : BbigT;
    #pragma unroll
    for (int mt = 0; mt < 4; ++mt) {
        int r = r0 + mt;
        union { ushort_t u[4]; uint2 v; } pk;
        #pragma unroll
        for (int reg = 0; reg < 4; ++reg) {
            int s = s0 + quad * 4 + reg;
            float mv = mask[(size_t)s * R + r];
            pk.u[reg] = f2bf((acc[mt][reg] + bias) * mv);
        }
        *(uint2*)&dst[((size_t)r * CH + c) * S + s0 + quad * 4] = pk.v;
    }
}

// ---------------------------------------------------------------------------
// K2: FUSED outer-product + projection (R4 math, fixed data paths).
// Block = 8 i x 8 j = 64 pairs, 512 thr (8 waves); wave w owns i = ib*8+w.
// Per e-chunk (4 e's):
//   - B slice (32 rows x 128 s, 8 KB) staged in LDS, double-buffered,
//     register-prefetched (was: lane-scattered global loads x8 waves)
//   - stage-1 MFMA -> oc LDS (16 KB, xor-swizzled)
//   - stage-2 MFMA: oc x WTp(global/L2) -> out accum (z-partitioned by wave)
// OC never touches HBM; ws shrinks to 4.5 MB.
// ---------------------------------------------------------------------------
__global__ __launch_bounds__(512, 4) void k_fuse(
    const ushort_t* __restrict__ Abig, const ushort_t* __restrict__ BbigT,
    const ushort_t* __restrict__ WTp, const float* __restrict__ b_out,
    const float* __restrict__ scale, float* __restrict__ out) {
    __shared__ ushort_t oc[64 * 128];        // 16 KB
    __shared__ ushort_t shB[2][32 * 128];    // 2 x 8 KB, [el*8+j][s] swizzled
    int t = threadIdx.x;
    int w = t >> 6, lane = t & 63, quad = lane >> 4, l15 = lane & 15;
    int ib = blockIdx.x >> 5, jb = blockIdx.x & 31;
    int i_g = ib * 8 + w;
    int jj = l15 & 7, elb = l15 >> 3;

    // A-frags for this wave's i-strip (register-resident, coalesced loads)
    short8 af[2][4];
    #pragma unroll
    for (int mt = 0; mt < 2; ++mt)
        #pragma unroll
        for (int ks = 0; ks < 4; ++ks)
            af[mt][ks] = *(const short8*)
                &Abig[((size_t)i_g * 32 + mt * 16 + l15) * S + ks * 32 + quad * 8];

    // B staging: thread t owns LDS row r2 = t>>4 (0..31), 16B chunk ck = t&15
    // global row = jb*256 + (r2&7)*32 + ec*4 + (r2>>3)
    int r2 = t >> 4, ck = t & 15;
    const ushort_t* gB = BbigT
        + ((size_t)jb * 256 + (r2 & 7) * 32 + (r2 >> 3)) * S + ck * 8;
    ushort_t* bdst[2];
    bdst[0] = &shB[0][r2 * 128 + ((ck ^ (r2 & 15)) << 3)];
    bdst[1] = &shB[1][r2 * 128 + ((ck ^ (r2 & 15)) << 3)];
    uint4 breg = *(const uint4*)&gB[0];      // prefetch ec=0 (e += 4 <=> +512)

    const ushort_t* Wp = WTp + (size_t)(w * 16 + l15) * 1024 + quad * 8;
    int pwr = w * 8 + jj;                    // oc pair-row this lane writes

    f32x4 acc2[4];
    #pragma unroll
    for (int pt = 0; pt < 4; ++pt) acc2[pt] = (f32x4)(0.f);

    for (int ec = 0; ec < 8; ++ec) {
        int buf = ec & 1;
        *(uint4*)bdst[buf] = breg;
        if (ec < 7) breg = *(const uint4*)&gB[(ec + 1) * 512];
        __syncthreads();   // publishes shB[buf]; closes prev stage-2 oc reads

        // ---- stage-1: OC chunk (e = ec*4 .. ec*4+3) ----
        f32x4 acc1[2][2];
        #pragma unroll
        for (int a = 0; a < 2; a++)
            #pragma unroll
            for (int b = 0; b < 2; b++) acc1[a][b] = (f32x4)(0.f);
        #pragma unroll
        for (int ks = 0; ks < 4; ++ks) {
            int chq = ks * 4 + quad;
            int r20 = elb * 8 + jj;          // nt=0: e = ec*4 + elb
            int r21 = r20 + 16;              // nt=1: e = ec*4 + 2 + elb
            short8 bf0 = *(const short8*)
                &shB[buf][r20 * 128 + ((chq ^ (r20 & 15)) << 3)];
            short8 bf1 = *(const short8*)
                &shB[buf][r21 * 128 + ((chq ^ (r21 & 15)) << 3)];
            #pragma unroll
            for (int mt = 0; mt < 2; ++mt) {
                acc1[mt][0] = __builtin_amdgcn_mfma_f32_16x16x32_bf16(
                    af[mt][ks], bf0, acc1[mt][0], 0, 0, 0);
                acc1[mt][1] = __builtin_amdgcn_mfma_f32_16x16x32_bf16(
                    af[mt][ks], bf1, acc1[mt][1], 0, 0, 0);
            }
        }
        // pack to oc: lane's 4 regs = 4 consecutive c at (pair pwr, e)
        #pragma unroll
        for (int mt = 0; mt < 2; ++mt) {
            int c00 = mt * 16 + quad * 4;
            #pragma unroll
            for (int nt = 0; nt < 2; ++nt) {
                int el = nt * 2 + elb;
                int k2l = el * 32 + c00;
                int cc = k2l >> 3;
                union { ushort_t u[4]; uint2 v; } pk;
                #pragma unroll
                for (int reg = 0; reg < 4; ++reg)
                    pk.u[reg] = f2bf(acc1[mt][nt][reg]);
                *(uint2*)((char*)oc + pwr * 256 + ((cc ^ (pwr & 7)) << 4)
                          + ((k2l & 7) << 1)) = pk.v;
            }
        }
        __syncthreads();   // publishes oc
        // ---- stage-2: out += OC_chunk x WTp_chunk (wave owns 16 z) ----
        #pragma unroll
        for (int ksl = 0; ksl < 4; ++ksl) {
            short8 wf = *(const short8*)&Wp[ec * 128 + ksl * 32];
            #pragma unroll
            for (int pt = 0; pt < 4; ++pt) {
                int pp = pt * 16 + l15;
                int cc = ksl * 4 + quad;
                short8 of = *(const short8*)
                    ((const char*)oc + pp * 256 + ((cc ^ (pp & 7)) << 4));
                acc2[pt] = __builtin_amdgcn_mfma_f32_16x16x32_bf16(
                    of, wf, acc2[pt], 0, 0, 0);
            }
        }
    }

    // ---- epilogue: bias + 1/(eps+norm) scale ----
    float bz = b_out[w * 16 + l15];
    #pragma unroll
    for (int pt = 0; pt < 4; ++pt) {
        #pragma unroll
        for (int reg = 0; reg < 4; ++reg) {
            int pp = pt * 16 + quad * 4 + reg;
            int pg = (ib * 8 + (pp >> 3)) * R + jb * 8 + (pp & 7);
            out[(size_t)pg * CZ + w * 16 + l15] = (acc2[pt][reg] + bz) * scale[pg];
        }
    }
}

// ---------------------------------------------------------------------------
extern "C" void kernel_launch(void* const* d_in, const int* in_sizes, int n_in,
                              void* d_out, int out_size, void* d_ws, size_t ws_size,
                              hipStream_t stream) {
    const float* m    = (const float*)d_in[0];
    const float* mask = (const float*)d_in[1];
    const float* g    = (const float*)d_in[2];
    const float* be   = (const float*)d_in[3];
    const float* w1   = (const float*)d_in[4];
    const float* b1   = (const float*)d_in[5];
    const float* w2   = (const float*)d_in[6];
    const float* b2   = (const float*)d_in[7];
    const float* wo   = (const float*)d_in[8];
    const float* bo   = (const float*)d_in[9];
    float* out = (float*)d_out;

    char* ws = (char*)d_ws;
    ushort_t* Abig  = (ushort_t*)ws;                        // 2 MB
    ushort_t* BbigT = Abig + (size_t)R * CH * S;            // 2 MB
    ushort_t* WTp   = BbigT + (size_t)R * CH * S;           // 256 KB
    ushort_t* WcatT = WTp + (size_t)CZ * CH * CH;           // 32 KB
    float*    scale = (float*)(WcatT + (size_t)64 * CM);    // 256 KB

    k_prep<<<448, 256, 0, stream>>>(mask, wo, w1, w2, scale, WTp, WcatT);
    k_lnproj<<<512, 256, 0, stream>>>(m, mask, g, be, b1, b2, WcatT, Abig, BbigT);
    k_fuse<<<1024, 512, 0, stream>>>(Abig, BbigT, WTp, bo, scale, out);
}